// Round 11
// baseline (39.094 us; speedup 1.0000x reference)
//
#include <hip/hip_runtime.h>

#ifndef FLT_MAX
#define FLT_MAX 3.402823466e+38f
#endif

typedef float v2f __attribute__((ext_vector_type(2)));
typedef float v4f __attribute__((ext_vector_type(4)));
typedef float sf8 __attribute__((ext_vector_type(8)));

__device__ __forceinline__ float rlanef(float v, int l) {
    return __uint_as_float(__builtin_amdgcn_readlane(__float_as_uint(v), l));
}

__device__ __forceinline__ float sel3(int i, float a, float b, float c) {
    return i == 0 ? a : (i == 1 ? b : c);
}

__device__ __forceinline__ float sel4(int i, float a, float b, float c, float d) {
    return i == 0 ? a : (i == 1 ? b : (i == 2 ? c : d));
}

// Deterministic d2 (scalar): sub,sub,sub,mul,fma,fma — element-wise identical
// to the packed pipeline, so phase-2 recomputed values are bit-identical.
__device__ __forceinline__ float d2f(float ax, float ay, float az,
                                     float bx, float by, float bz) {
    const float dx = __fsub_rn(ax, bx);
    const float dy = __fsub_rn(ay, by);
    const float dz = __fsub_rn(az, bz);
    return __builtin_fmaf(dx, dx, __builtin_fmaf(dy, dy, __fmul_rn(dz, dz)));
}

__device__ __forceinline__ v2f d2p(v2f ax, v2f ay, v2f az, v2f bx, v2f by, v2f bz) {
    const v2f dx = ax - bx, dy = ay - by, dz = az - bz;
    return __builtin_elementwise_fma(dx, dx,
           __builtin_elementwise_fma(dy, dy, dz * dz));
}

// ---------- Kernel 1: gather-once cluster coords table -----------------------
// T[c] = SoA [3][64] f32 (stride 192 floats = 768B).
__global__ __launch_bounds__(256) void build_table_kernel(
    const float* __restrict__ data,
    const int*   __restrict__ clusts,
    float*       __restrict__ T,
    int C)
{
    const int c = blockIdx.x * 4 + (threadIdx.x >> 6);
    const int p = threadIdx.x & 63;
    if (c >= C) return;
    const int pid = clusts[c * 64 + p];
    const float4 d = *reinterpret_cast<const float4*>(data + (size_t)pid * 4);
    float* row = T + (size_t)c * 192;
    row[p]       = d.y;
    row[p + 64]  = d.z;
    row[p + 128] = d.w;
}

// ---------- Kernel 2: scan with SCALAR-pipe column broadcast -----------------
// One edge per 64-lane wave, lane = row (x1[lane] in 3 VGPRs). Columns are
// wave-uniform -> streamed via s_load_dwordx8 into SGPRs (K-cache; zero LDS
// pipe cost, zero VALU cost) and consumed directly as the single allowed SGPR
// operand of v_pk_* ops. The s_waitcnt lives INSIDE the asm block whose
// outputs feed the consumers, so ordering is enforced by dataflow.
__global__ __launch_bounds__(256) void clustgeo_sload_kernel(
    const float* __restrict__ T,       // (C,3,64) f32 dense table
    const int*   __restrict__ eidx,    // (2,E)  int
    float*       __restrict__ out,     // (E,19) f32
    int E)
{
    const int wave = threadIdx.x >> 6;
    const int lane = threadIdx.x & 63;
    const int e = blockIdx.x * 4 + wave;
    const int ec = e < E ? e : (E - 1);

    // Cluster ids are wave-uniform; force them scalar.
    const int ca = __builtin_amdgcn_readfirstlane(eidx[ec]);
    const int cb = __builtin_amdgcn_readfirstlane(eidx[E + ec]);
    const float* ta = T + (size_t)ca * 192;
    const float* tb = T + (size_t)cb * 192;

    // Rows lane-linear (coalesced VMEM).
    const float rx = ta[lane];
    const float ry = ta[64 + lane];
    const float rz = ta[128 + lane];
    const v2f rxx = {rx, rx}, ryy = {ry, ry}, rzz = {rz, rz};

    v2f a01 = {FLT_MAX, FLT_MAX};
    v2f a23 = {FLT_MAX, FLT_MAX};

#define COLPAIR(XS, YS, ZS, U, ACC) do {                                       \
    const v2f cx = __builtin_shufflevector(XS, XS, 2*(U), 2*(U)+1);            \
    const v2f cy = __builtin_shufflevector(YS, YS, 2*(U), 2*(U)+1);            \
    const v2f cz = __builtin_shufflevector(ZS, ZS, 2*(U), 2*(U)+1);            \
    ACC = __builtin_elementwise_min(ACC, d2p(rxx, ryy, rzz, cx, cy, cz));      \
} while (0)

#define CHUNK(K) do {                                                          \
    sf8 Xs, Ys, Zs;                                                            \
    asm volatile("s_load_dwordx8 %0, %3, %4\n\t"                               \
                 "s_load_dwordx8 %1, %3, %5\n\t"                               \
                 "s_load_dwordx8 %2, %3, %6\n\t"                               \
                 "s_waitcnt lgkmcnt(0)"                                        \
                 : "=&s"(Xs), "=&s"(Ys), "=&s"(Zs)                             \
                 : "s"(tb), "n"((K) * 32), "n"(256 + (K) * 32),                \
                   "n"(512 + (K) * 32));                                       \
    COLPAIR(Xs, Ys, Zs, 0, a01);                                               \
    COLPAIR(Xs, Ys, Zs, 1, a23);                                               \
    COLPAIR(Xs, Ys, Zs, 2, a01);                                               \
    COLPAIR(Xs, Ys, Zs, 3, a23);                                               \
} while (0)

    CHUNK(0); CHUNK(1); CHUNK(2); CHUNK(3);
    CHUNK(4); CHUNK(5); CHUNK(6); CHUNK(7);
#undef CHUNK
#undef COLPAIR

    const float rowmin = fminf(fminf(a01.x, a01.y), fminf(a23.x, a23.y));

    // Wave min of rowmin.
    float bm = rowmin;
    #pragma unroll
    for (int off = 32; off; off >>= 1) bm = fminf(bm, __shfl_xor(bm, off, 64));

    // Lowest row attaining the min == lowest i (numpy row-major first).
    const unsigned long long mi = __ballot(rowmin == bm);
    const int i1 = (int)__ffsll(mi) - 1;
    const float v1x = rlanef(rx, i1);
    const float v1y = rlanef(ry, i1);
    const float v1z = rlanef(rz, i1);

    // Phase 2: lane = col; reload x2[lane] (coalesced VMEM), recompute row i1
    // with the bit-identical scalar pipeline; first match = exact numpy j.
    const float cx2 = tb[lane];
    const float cy2 = tb[64 + lane];
    const float cz2 = tb[128 + lane];
    const float dj = d2f(v1x, v1y, v1z, cx2, cy2, cz2);
    const unsigned long long mj = __ballot(dj == bm);
    const int i2 = (int)__ffsll(mj) - 1;
    const float v2x = rlanef(cx2, i2);
    const float v2y = rlanef(cy2, i2);
    const float v2z = rlanef(cz2, i2);

    float dx = v1x - v2x, dy = v1y - v2y, dz = v1z - v2z;
    const float lend = sqrtf(dx * dx + dy * dy + dz * dz);
    if (lend > 0.f) { dx /= lend; dy /= lend; dz /= lend; }

    if (lane < 19 && e < E) {
        float o;
        if (lane < 3)       o = sel3(lane,     v1x, v1y, v1z);
        else if (lane < 6)  o = sel3(lane - 3, v2x, v2y, v2z);
        else if (lane < 9)  o = sel3(lane - 6, dx, dy, dz);
        else if (lane == 9) o = lend;
        else {
            const int k = lane - 10;
            o = sel3(k / 3, dx, dy, dz) * sel3(k % 3, dx, dy, dz);
        }
        out[(size_t)e * 19 + lane] = o;
    }
}

// ---------- Fallback (R9 kernel; used only if ws too small) ------------------
#define SLICE 196
__global__ __launch_bounds__(256, 4) void clustgeo_edge_fallback(
    const float* __restrict__ data,
    const int*   __restrict__ clusts,
    const int*   __restrict__ eidx,
    float*       __restrict__ out,
    int E)
{
    const int wave = threadIdx.x >> 6;
    const int lane = threadIdx.x & 63;
    const int t    = lane & 15;
    const int gsh  = lane & 48;
    const int e    = blockIdx.x * 16 + wave * 4 + (lane >> 4);
    const int ec   = e < E ? e : (E - 1);

    __shared__ __align__(16) float sx[4][4][SLICE];

    const int ca = eidx[ec];
    const int cb = eidx[E + ec];
    const int4 P1 = *reinterpret_cast<const int4*>(clusts + ca * 64 + 4 * t);
    const int4 P2 = *reinterpret_cast<const int4*>(clusts + cb * 64 + 4 * t);
    const float4 q10 = *reinterpret_cast<const float4*>(data + (size_t)P1.x * 4);
    const float4 q11 = *reinterpret_cast<const float4*>(data + (size_t)P1.y * 4);
    const float4 q12 = *reinterpret_cast<const float4*>(data + (size_t)P1.z * 4);
    const float4 q13 = *reinterpret_cast<const float4*>(data + (size_t)P1.w * 4);
    const float4 q20 = *reinterpret_cast<const float4*>(data + (size_t)P2.x * 4);
    const float4 q21 = *reinterpret_cast<const float4*>(data + (size_t)P2.y * 4);
    const float4 q22 = *reinterpret_cast<const float4*>(data + (size_t)P2.z * 4);
    const float4 q23 = *reinterpret_cast<const float4*>(data + (size_t)P2.w * 4);
    const v4f RX = {q10.y, q11.y, q12.y, q13.y};
    const v4f RY = {q10.z, q11.z, q12.z, q13.z};
    const v4f RZ = {q10.w, q11.w, q12.w, q13.w};
    const v4f CX = {q20.y, q21.y, q22.y, q23.y};
    const v4f CY = {q20.z, q21.z, q22.z, q23.z};
    const v4f CZ = {q20.w, q21.w, q22.w, q23.w};

    float* slice = &sx[wave][lane >> 4][0];
    *reinterpret_cast<v4f*>(slice + 4 * t)       = CX;
    *reinterpret_cast<v4f*>(slice + 64 + 4 * t)  = CY;
    *reinterpret_cast<v4f*>(slice + 128 + 4 * t) = CZ;

    const v4f* SL = reinterpret_cast<const v4f*>(slice);
    v2f a0 = {FLT_MAX, FLT_MAX}, a1 = {FLT_MAX, FLT_MAX};
    v2f a2 = {FLT_MAX, FLT_MAX}, a3 = {FLT_MAX, FLT_MAX};
    #pragma unroll 2
    for (int g = 0; g < 16; ++g) {
        const v4f X = SL[g];
        const v4f Y = SL[16 + g];
        const v4f Z = SL[32 + g];
        const v2f xlo = X.xy, xhi = X.zw, ylo = Y.xy, yhi = Y.zw, zlo = Z.xy, zhi = Z.zw;
        a0 = __builtin_elementwise_min(a0, d2p((v2f){RX.x,RX.x},(v2f){RY.x,RY.x},(v2f){RZ.x,RZ.x}, xlo, ylo, zlo));
        a0 = __builtin_elementwise_min(a0, d2p((v2f){RX.x,RX.x},(v2f){RY.x,RY.x},(v2f){RZ.x,RZ.x}, xhi, yhi, zhi));
        a1 = __builtin_elementwise_min(a1, d2p((v2f){RX.y,RX.y},(v2f){RY.y,RY.y},(v2f){RZ.y,RZ.y}, xlo, ylo, zlo));
        a1 = __builtin_elementwise_min(a1, d2p((v2f){RX.y,RX.y},(v2f){RY.y,RY.y},(v2f){RZ.y,RZ.y}, xhi, yhi, zhi));
        a2 = __builtin_elementwise_min(a2, d2p((v2f){RX.z,RX.z},(v2f){RY.z,RY.z},(v2f){RZ.z,RZ.z}, xlo, ylo, zlo));
        a2 = __builtin_elementwise_min(a2, d2p((v2f){RX.z,RX.z},(v2f){RY.z,RY.z},(v2f){RZ.z,RZ.z}, xhi, yhi, zhi));
        a3 = __builtin_elementwise_min(a3, d2p((v2f){RX.w,RX.w},(v2f){RY.w,RY.w},(v2f){RZ.w,RZ.w}, xlo, ylo, zlo));
        a3 = __builtin_elementwise_min(a3, d2p((v2f){RX.w,RX.w},(v2f){RY.w,RY.w},(v2f){RZ.w,RZ.w}, xhi, yhi, zhi));
    }
    const float m0 = fminf(a0.x, a0.y);
    const float m1 = fminf(a1.x, a1.y);
    const float m2 = fminf(a2.x, a2.y);
    const float m3 = fminf(a3.x, a3.y);
    float bmn = fminf(fminf(m0, m1), fminf(m2, m3));
    #pragma unroll
    for (int off = 8; off; off >>= 1) bmn = fminf(bmn, __shfl_xor(bmn, off, 64));
    const unsigned g0 = (unsigned)(__ballot(m0 == bmn) >> gsh) & 0xFFFFu;
    const unsigned g1 = (unsigned)(__ballot(m1 == bmn) >> gsh) & 0xFFFFu;
    const unsigned g2 = (unsigned)(__ballot(m2 == bmn) >> gsh) & 0xFFFFu;
    const unsigned g3 = (unsigned)(__ballot(m3 == bmn) >> gsh) & 0xFFFFu;
    const int t1 = __builtin_ctz(g0 | g1 | g2 | g3);
    const int s1 = (g0 >> t1) & 1 ? 0 : (g1 >> t1) & 1 ? 1 : (g2 >> t1) & 1 ? 2 : 3;
    const float v1x = __shfl(sel4(s1, RX.x, RX.y, RX.z, RX.w), gsh + t1, 64);
    const float v1y = __shfl(sel4(s1, RY.x, RY.y, RY.z, RY.w), gsh + t1, 64);
    const float v1z = __shfl(sel4(s1, RZ.x, RZ.y, RZ.z, RZ.w), gsh + t1, 64);
    const float d0 = d2f(v1x, v1y, v1z, CX.x, CY.x, CZ.x);
    const float d1 = d2f(v1x, v1y, v1z, CX.y, CY.y, CZ.y);
    const float d2_ = d2f(v1x, v1y, v1z, CX.z, CY.z, CZ.z);
    const float d3 = d2f(v1x, v1y, v1z, CX.w, CY.w, CZ.w);
    const unsigned h0 = (unsigned)(__ballot(d0 == bmn) >> gsh) & 0xFFFFu;
    const unsigned h1 = (unsigned)(__ballot(d1 == bmn) >> gsh) & 0xFFFFu;
    const unsigned h2 = (unsigned)(__ballot(d2_ == bmn) >> gsh) & 0xFFFFu;
    const unsigned h3 = (unsigned)(__ballot(d3 == bmn) >> gsh) & 0xFFFFu;
    const int t2 = __builtin_ctz(h0 | h1 | h2 | h3);
    const int s2 = (h0 >> t2) & 1 ? 0 : (h1 >> t2) & 1 ? 1 : (h2 >> t2) & 1 ? 2 : 3;
    const float v2x = __shfl(sel4(s2, CX.x, CX.y, CX.z, CX.w), gsh + t2, 64);
    const float v2y = __shfl(sel4(s2, CY.x, CY.y, CY.z, CY.w), gsh + t2, 64);
    const float v2z = __shfl(sel4(s2, CZ.x, CZ.y, CZ.z, CZ.w), gsh + t2, 64);
    float dx = v1x - v2x, dy = v1y - v2y, dz = v1z - v2z;
    const float lend = sqrtf(dx * dx + dy * dy + dz * dz);
    if (lend > 0.f) { dx /= lend; dy /= lend; dz /= lend; }
    if (e < E) {
        float* orow = out + (size_t)e * 19;
        float o;
        if (t < 3)       o = sel3(t,     v1x, v1y, v1z);
        else if (t < 6)  o = sel3(t - 3, v2x, v2y, v2z);
        else if (t < 9)  o = sel3(t - 6, dx, dy, dz);
        else if (t == 9) o = lend;
        else {
            const int k = t - 10;
            o = sel3(k / 3, dx, dy, dz) * sel3(k % 3, dx, dy, dz);
        }
        orow[t] = o;
        if (t < 3) {
            const int k = t + 6;
            orow[16 + t] = sel3(k / 3, dx, dy, dz) * sel3(k % 3, dx, dy, dz);
        }
    }
}

extern "C" void kernel_launch(void* const* d_in, const int* in_sizes, int n_in,
                              void* d_out, int out_size, void* d_ws, size_t ws_size,
                              hipStream_t stream) {
    const float* data   = (const float*)d_in[0];
    const int*   clusts = (const int*)d_in[1];
    const int*   eidx   = (const int*)d_in[2];
    float*       out    = (float*)d_out;
    const int E = in_sizes[2] / 2;            // edge_index is (2, E)
    const int C = in_sizes[1] / 64;           // clusts is (C, 64)
    const size_t tbytes = (size_t)C * 192 * sizeof(float);

    if (ws_size >= tbytes) {
        float* T = (float*)d_ws;
        build_table_kernel<<<(C + 3) / 4, 256, 0, stream>>>(data, clusts, T, C);
        clustgeo_sload_kernel<<<(E + 3) / 4, 256, 0, stream>>>(T, eidx, out, E);
    } else {
        clustgeo_edge_fallback<<<(E + 15) / 16, 256, 0, stream>>>(data, clusts, eidx, out, E);
    }
}